// Round 3
// baseline (813.435 us; speedup 1.0000x reference)
//
#include <hip/hip_runtime.h>

#define BB 64
#define TT 1024
#define CC 2
#define NN 128

#define REP16(M) M(0)M(1)M(2)M(3)M(4)M(5)M(6)M(7)M(8)M(9)M(10)M(11)M(12)M(13)M(14)M(15)

// fp32 -> bf16 bits, round-to-nearest-even (inputs are never NaN here)
static __device__ __forceinline__ unsigned f2bf(float x) {
    const unsigned u = __float_as_uint(x);
    return (u + 0x7FFFu + ((u >> 16) & 1u)) >> 16;
}
static __device__ __forceinline__ unsigned pk2(float lo, float hi) {
    return f2bf(lo) | (f2bf(hi) << 16);
}

// D.f32 += S0.bf16[0]*S1.bf16[0] + S0.bf16[1]*S1.bf16[1]  (VOP3P, full rate)
#define DOT(acc, pp, ee) \
    asm("v_dot2_f32_bf16 %0, %1, %2, %0" : "+v"(acc) : "v"(pp), "v"(ee));

// ROUND-3 CHANGE: exp(E) column j lives in the AGPR file (64 AGPRs/lane).
// Evidence: rounds 0/1 reported VGPR_Count=44-48 — 64 "pinned" E words can
// NOT be resident in 44 VGPRs, so the allocator was spilling E to private
// scratch and reloading ~16 b128/step from L2 (~200cyc each, little overlap
// because there was no register room to hoist) => the ~800 cyc/step VMEM
// stall (invisible in FETCH_SIZE: scratch is L2-resident; low VALUBusy).
// Round 2 (E in LDS) swapped that for 32 unique-address ds_read_b128/step
// on the shared LDS pipe (~12cyc each) => worse. AGPRs are the one storage
// that is (a) per-lane, (b) full-rate to read (v_accvgpr_read is plain
// VALU), (c) completely unused here, so the allocator has zero motive to
// spill. Explicit accvgpr_write pins placement.
#define E_INIT(c) \
    unsigned ae##c##_0, ae##c##_1, ae##c##_2, ae##c##_3; \
    asm("v_accvgpr_write_b32 %0, %1" : "=a"(ae##c##_0) \
        : "v"(pk2(__expf(tr[(8*(c)+0)*NN + j]), __expf(tr[(8*(c)+1)*NN + j])))); \
    asm("v_accvgpr_write_b32 %0, %1" : "=a"(ae##c##_1) \
        : "v"(pk2(__expf(tr[(8*(c)+2)*NN + j]), __expf(tr[(8*(c)+3)*NN + j])))); \
    asm("v_accvgpr_write_b32 %0, %1" : "=a"(ae##c##_2) \
        : "v"(pk2(__expf(tr[(8*(c)+4)*NN + j]), __expf(tr[(8*(c)+5)*NN + j])))); \
    asm("v_accvgpr_write_b32 %0, %1" : "=a"(ae##c##_3) \
        : "v"(pk2(__expf(tr[(8*(c)+6)*NN + j]), __expf(tr[(8*(c)+7)*NN + j]))));

// 8 MACs: one b128 broadcast read (4 packed p-pairs) + 4 AGPR reads + 4 dot2.
// volatile on the reads: they are loop-invariant asm, and a non-volatile
// version would be LICM-hoisted => 64 VGPR copies live across the loop =>
// right back to the spill. volatile keeps the reads per-iteration.
#define MV(c) { const uint4 q = pb[c]; unsigned e0, e1, e2, e3; \
    asm volatile("v_accvgpr_read_b32 %0, %1" : "=v"(e0) : "a"(ae##c##_0)); \
    asm volatile("v_accvgpr_read_b32 %0, %1" : "=v"(e1) : "a"(ae##c##_1)); \
    asm volatile("v_accvgpr_read_b32 %0, %1" : "=v"(e2) : "a"(ae##c##_2)); \
    asm volatile("v_accvgpr_read_b32 %0, %1" : "=v"(e3) : "a"(ae##c##_3)); \
    DOT(a0, q.x, e0) DOT(a1, q.y, e1) \
    DOT(a2, q.z, e2) DOT(a3, q.w, e3) }

// Raw workgroup barrier: producer-visibility via lgkmcnt(0) ONLY (global
// prefetch loads stay in flight across the barrier). WAR safety on the
// double-buffered p: each wave's lgkmcnt(0) at the NEXT barrier drains its
// reads before any wave re-writes that buffer two iterations later.
static __device__ __forceinline__ void wg_barrier() {
    asm volatile("s_waitcnt lgkmcnt(0)" ::: "memory");
    __builtin_amdgcn_s_barrier();
    asm volatile("" ::: "memory");
}

// One workgroup (128 thr = 2 waves) per (b,c) chain; thread j owns tag j
// and E column j as 64 packed-bf16 words in AGPRs.
//
// Critical-path factoring (kept from round 1): alpha_t = S_t + log(s_t) + e_t,
//   p_{t+1} = exp(alpha_t - S_{t+1}) = s_t * exp(S_t + e_t - S_{t+1})
// so __expf/__logf run off the serial chain (log only on thread 0's
// shift side-path, which has a full step of slack).
__global__ __launch_bounds__(128, 1) __attribute__((amdgpu_waves_per_eu(1, 1)))
void crf_logz_kernel(const float* __restrict__ emissions,
                     const int* __restrict__ lengths,
                     const float* __restrict__ transitions,
                     const float* __restrict__ start_trans,
                     const float* __restrict__ end_trans,
                     float* __restrict__ out)
{
    const int bc = blockIdx.x;
    const int b  = bc >> 1;
    const int c  = bc & 1;
    const int j  = threadIdx.x;            // 0..127, owns tag j

    __shared__ __align__(16) unsigned short pbufs[2][NN];  // bf16 p, double-buffered
    __shared__ float shbuf[2];             // shift broadcast (alpha_t[0]), parity-buffered
    __shared__ float red[NN];              // final reduction scratch

    const float* tr = transitions + c * NN * NN;
    REP16(E_INIT)                          // 64 AGPRs = 128 bf16 E values, pinned

    const int len  = lengths[b];           // in [T/2, T]
    const int tmax = len - 1;

    // emissions[b][t][c][*]; t-stride = CC*NN floats; coalesced per wave
    const float* emisb = emissions + ((size_t)b * TT * CC + c) * NN;

    const float alpha0 = start_trans[c * NN + j] + emisb[j];  // alpha_0[j]
    if (j == 0) shbuf[0] = alpha0;         // S_2 = alpha_0[0]; visible after barrier t=1

    // p_1 = exp(alpha_0 - S_1) with S_1 = 0 (|alpha_0| < ~12)
    unsigned pbits = f2bf(__expf(alpha0));
    float Scur = 0.f;                      // S_t for t = 1

    // 2-deep register emission pipeline (stays in flight across raw barriers)
    const int t1 = (1 < tmax) ? 1 : tmax, t2 = (2 < tmax) ? 2 : tmax;
    float ecur = emisb[(size_t)t1 * (CC * NN) + j];   // e_t
    float enx  = emisb[(size_t)t2 * (CC * NN) + j];   // e_{t+1}

    float s = 0.f, Sfin = 0.f, efin = ecur;

    for (int t = 1; t < len; ++t) {
        pbufs[t & 1][j] = (unsigned short)pbits;   // p_t, packed last iteration
        wg_barrier();                              // lgkm-only: vmcnt stays in flight

        // prefetch emission for t+2 (clamped); never drained by the barrier
        const int tp = (t + 2 <= tmax) ? (t + 2) : tmax;
        const float el = emisb[(size_t)tp * (CC * NN) + j];

        const float Snxt = shbuf[(t - 1) & 1];     // S_{t+1} = alpha_{t-1}[0]
        const float f = __expf(Scur + ecur - Snxt); // || with dots (no dep on s)

        const uint4* __restrict__ pb = (const uint4*)pbufs[t & 1];
        float a0 = 0.f, a1 = 0.f, a2 = 0.f, a3 = 0.f;
        REP16(MV)                          // 16 p-broadcasts + 64 AGPR reads + 64 dot2
        s = (a0 + a1) + (a2 + a3);         // s_t[j]

        // S_{t+2} = alpha_t[0]; thread 0's log has a step of slack
        if (j == 0) shbuf[t & 1] = Scur + __logf(s) + ecur;

        pbits = f2bf(s * f);               // p_{t+1}[j] -> bf16 (critical: 1 mul + pack)

        Sfin = Scur; efin = ecur;          // snapshot for epilogue
        Scur = Snxt; ecur = enx; enx = el;
    }

    // alpha_{len-1}[j] = S_{len-1} + log(s_{len-1}[j]) + e_{len-1}[j]
    const float alpha = (tmax == 0) ? alpha0 : (Sfin + __logf(s) + efin);

    // final logsumexp over tags
    red[j] = alpha + end_trans[c * NN + j];
    __syncthreads();
    if (j < 64) {
        const float x = red[j], y = red[j + 64];
        float m = fmaxf(x, y);
        #pragma unroll
        for (int off = 32; off > 0; off >>= 1)
            m = fmaxf(m, __shfl_xor(m, off));
        float ssum = __expf(x - m) + __expf(y - m);
        #pragma unroll
        for (int off = 32; off > 0; off >>= 1)
            ssum += __shfl_xor(ssum, off);
        if (j == 0) out[b * CC + c] = m + __logf(ssum);
    }
}

extern "C" void kernel_launch(void* const* d_in, const int* in_sizes, int n_in,
                              void* d_out, int out_size, void* d_ws, size_t ws_size,
                              hipStream_t stream) {
    const float* emissions   = (const float*)d_in[0];
    const int*   lengths     = (const int*)d_in[1];
    const float* transitions = (const float*)d_in[2];
    const float* start_t     = (const float*)d_in[3];
    const float* end_t       = (const float*)d_in[4];
    float* out = (float*)d_out;

    crf_logz_kernel<<<BB * CC, NN, 0, stream>>>(
        emissions, lengths, transitions, start_t, end_t, out);
}

// Round 5
// 666.187 us; speedup vs baseline: 1.2210x; 1.2210x over previous
//
#include <hip/hip_runtime.h>

#define BB 64
#define TT 1024
#define CC 2
#define NN 128

#define REP8L(M) M(0)M(1)M(2)M(3)M(4)M(5)M(6)M(7)
#define REP8H(M) M(8)M(9)M(10)M(11)M(12)M(13)M(14)M(15)

// fp32 -> bf16 bits, round-to-nearest-even (inputs are never NaN here)
static __device__ __forceinline__ unsigned f2bf(float x) {
    const unsigned u = __float_as_uint(x);
    return (u + 0x7FFFu + ((u >> 16) & 1u)) >> 16;
}
static __device__ __forceinline__ unsigned pk2(float lo, float hi) {
    return f2bf(lo) | (f2bf(hi) << 16);
}

// D.f32 += S0.bf16[0]*S1.bf16[0] + S0.bf16[1]*S1.bf16[1]  (VOP3P, VGPR-only
// sources: R4 proved v_dot2 rejects AGPR operands on gfx950).
#define DOT(acc, pp, ee) \
    asm("v_dot2_f32_bf16 %0, %1, %2, %0" : "+v"(acc) : "v"(pp), "v"(ee));

// ROUND-5: split E residency.
// Evidence trail: VGPR_Count excludes AGPRs (R3 showed 52 with 64 explicit
// AGPRs), so R0/R1's "44 VGPRs" means the allocator AGPR-spilled E and
// emitted ~64 JIT v_accvgpr_read restores per wave per step inside the dot
// phase — the ~500-600 cyc/step gap. Fix: (a) LO half (k=0..63, 32 words)
// as plain C values — total live pressure ~90 regs now fits comfortably,
// removing the motive to spill; (b) HI half (k=64..127, 32 words) pinned
// in AGPRs, restored at the TOP of each iteration by non-volatile asm with
// a loop-variant dummy dep (no LICM, scheduler free) so the ~64 cyc of
// restore issue overlaps the ds_write/barrier/broadcast-latency window
// instead of serializing with the dots.
#define E_LO_INIT(c) \
    const unsigned ul##c##_0 = pk2(__expf(tr[(8*(c)+0)*NN + j]), __expf(tr[(8*(c)+1)*NN + j])); \
    const unsigned ul##c##_1 = pk2(__expf(tr[(8*(c)+2)*NN + j]), __expf(tr[(8*(c)+3)*NN + j])); \
    const unsigned ul##c##_2 = pk2(__expf(tr[(8*(c)+4)*NN + j]), __expf(tr[(8*(c)+5)*NN + j])); \
    const unsigned ul##c##_3 = pk2(__expf(tr[(8*(c)+6)*NN + j]), __expf(tr[(8*(c)+7)*NN + j]));

#define E_HI_INIT(c) \
    unsigned ae##c##_0, ae##c##_1, ae##c##_2, ae##c##_3; \
    asm volatile("v_accvgpr_write_b32 %0, %1" : "=a"(ae##c##_0) \
        : "v"(pk2(__expf(tr[(8*(c)+0)*NN + j]), __expf(tr[(8*(c)+1)*NN + j])))); \
    asm volatile("v_accvgpr_write_b32 %0, %1" : "=a"(ae##c##_1) \
        : "v"(pk2(__expf(tr[(8*(c)+2)*NN + j]), __expf(tr[(8*(c)+3)*NN + j])))); \
    asm volatile("v_accvgpr_write_b32 %0, %1" : "=a"(ae##c##_2) \
        : "v"(pk2(__expf(tr[(8*(c)+4)*NN + j]), __expf(tr[(8*(c)+5)*NN + j])))); \
    asm volatile("v_accvgpr_write_b32 %0, %1" : "=a"(ae##c##_3) \
        : "v"(pk2(__expf(tr[(8*(c)+6)*NN + j]), __expf(tr[(8*(c)+7)*NN + j]))));

// Per-iteration restore: non-volatile (schedulable), loop-variant dummy %2
// prevents LICM from hoisting 32 live copies across the whole loop.
#define E_HI_RESTORE(c) \
    unsigned eh##c##_0, eh##c##_1, eh##c##_2, eh##c##_3; \
    asm("v_accvgpr_read_b32 %0, %1" : "=v"(eh##c##_0) : "a"(ae##c##_0), "v"(tv)); \
    asm("v_accvgpr_read_b32 %0, %1" : "=v"(eh##c##_1) : "a"(ae##c##_1), "v"(tv)); \
    asm("v_accvgpr_read_b32 %0, %1" : "=v"(eh##c##_2) : "a"(ae##c##_2), "v"(tv)); \
    asm("v_accvgpr_read_b32 %0, %1" : "=v"(eh##c##_3) : "a"(ae##c##_3), "v"(tv));

// 8 MACs per chunk: one b128 broadcast read (4 packed p-pairs) + 4 dot2.
#define MV_LO(c) { const uint4 q = pb[c]; \
    DOT(a0, q.x, ul##c##_0) DOT(a1, q.y, ul##c##_1) \
    DOT(a2, q.z, ul##c##_2) DOT(a3, q.w, ul##c##_3) }
#define MV_HI(c) { const uint4 q = pb[c]; \
    DOT(a0, q.x, eh##c##_0) DOT(a1, q.y, eh##c##_1) \
    DOT(a2, q.z, eh##c##_2) DOT(a3, q.w, eh##c##_3) }

// Raw workgroup barrier: producer-visibility via lgkmcnt(0) ONLY (global
// prefetch loads stay in flight across the barrier). WAR safety on the
// double-buffered p: each wave's lgkmcnt(0) at the NEXT barrier drains its
// reads before any wave re-writes that buffer two iterations later.
static __device__ __forceinline__ void wg_barrier() {
    asm volatile("s_waitcnt lgkmcnt(0)" ::: "memory");
    __builtin_amdgcn_s_barrier();
    asm volatile("" ::: "memory");
}

// One workgroup (128 thr = 2 waves) per (b,c) chain; thread j owns tag j.
// E column j: k=0..63 in arch VGPRs, k=64..127 in AGPRs (restored early
// each step).
//
// Critical-path factoring (kept): alpha_t = S_t + log(s_t) + e_t,
//   p_{t+1} = exp(alpha_t - S_{t+1}) = s_t * exp(S_t + e_t - S_{t+1})
// so __expf/__logf run off the serial chain (log only on thread 0's
// shift side-path, which has a full step of slack).
__global__ __launch_bounds__(128, 1) __attribute__((amdgpu_waves_per_eu(1, 1)))
void crf_logz_kernel(const float* __restrict__ emissions,
                     const int* __restrict__ lengths,
                     const float* __restrict__ transitions,
                     const float* __restrict__ start_trans,
                     const float* __restrict__ end_trans,
                     float* __restrict__ out)
{
    const int bc = blockIdx.x;
    const int b  = bc >> 1;
    const int c  = bc & 1;
    const int j  = threadIdx.x;            // 0..127, owns tag j

    __shared__ __align__(16) unsigned short pbufs[2][NN];  // bf16 p, double-buffered
    __shared__ float shbuf[2];             // shift broadcast (alpha_t[0]), parity-buffered
    __shared__ float red[NN];              // final reduction scratch

    const float* tr = transitions + c * NN * NN;
    REP8L(E_LO_INIT)                       // 32 VGPR words: exp(E[k=0..63][j])
    REP8H(E_HI_INIT)                       // 32 AGPR words: exp(E[k=64..127][j])

    const int len  = lengths[b];           // in [T/2, T]
    const int tmax = len - 1;

    // emissions[b][t][c][*]; t-stride = CC*NN floats; coalesced per wave
    const float* emisb = emissions + ((size_t)b * TT * CC + c) * NN;

    const float alpha0 = start_trans[c * NN + j] + emisb[j];  // alpha_0[j]
    if (j == 0) shbuf[0] = alpha0;         // S_2 = alpha_0[0]; visible after barrier t=1

    // p_1 = exp(alpha_0 - S_1) with S_1 = 0 (|alpha_0| < ~12)
    unsigned pbits = f2bf(__expf(alpha0));
    float Scur = 0.f;                      // S_t for t = 1

    // 2-deep register emission pipeline (stays in flight across raw barriers)
    const int t1 = (1 < tmax) ? 1 : tmax, t2 = (2 < tmax) ? 2 : tmax;
    float ecur = emisb[(size_t)t1 * (CC * NN) + j];   // e_t
    float enx  = emisb[(size_t)t2 * (CC * NN) + j];   // e_{t+1}

    float s = 0.f, Sfin = 0.f, efin = ecur;

    for (int t = 1; t < len; ++t) {
        const int tv = t;                  // loop-variant dummy for restore asm
        REP8H(E_HI_RESTORE)                // 32 accvgpr_read: overlap write/barrier

        pbufs[t & 1][j] = (unsigned short)pbits;   // p_t, packed last iteration
        wg_barrier();                              // lgkm-only: vmcnt stays in flight

        // prefetch emission for t+2 (clamped); never drained by the barrier
        const int tp = (t + 2 <= tmax) ? (t + 2) : tmax;
        const float el = emisb[(size_t)tp * (CC * NN) + j];

        const float Snxt = shbuf[(t - 1) & 1];     // S_{t+1} = alpha_{t-1}[0]
        const float f = __expf(Scur + ecur - Snxt); // || with dots (no dep on s)

        const uint4* __restrict__ pb = (const uint4*)pbufs[t & 1];
        float a0 = 0.f, a1 = 0.f, a2 = 0.f, a3 = 0.f;
        REP8H(MV_HI)                       // hi chunks first: frees restore temps
        REP8L(MV_LO)
        s = (a0 + a1) + (a2 + a3);         // s_t[j]

        // S_{t+2} = alpha_t[0]; thread 0's log has a step of slack
        if (j == 0) shbuf[t & 1] = Scur + __logf(s) + ecur;

        pbits = f2bf(s * f);               // p_{t+1}[j] -> bf16 (critical: 1 mul + pack)

        Sfin = Scur; efin = ecur;          // snapshot for epilogue
        Scur = Snxt; ecur = enx; enx = el;
    }

    // alpha_{len-1}[j] = S_{len-1} + log(s_{len-1}[j]) + e_{len-1}[j]
    const float alpha = (tmax == 0) ? alpha0 : (Sfin + __logf(s) + efin);

    // final logsumexp over tags
    red[j] = alpha + end_trans[c * NN + j];
    __syncthreads();
    if (j < 64) {
        const float x = red[j], y = red[j + 64];
        float m = fmaxf(x, y);
        #pragma unroll
        for (int off = 32; off > 0; off >>= 1)
            m = fmaxf(m, __shfl_xor(m, off));
        float ssum = __expf(x - m) + __expf(y - m);
        #pragma unroll
        for (int off = 32; off > 0; off >>= 1)
            ssum += __shfl_xor(ssum, off);
        if (j == 0) out[b * CC + c] = m + __logf(ssum);
    }
}

extern "C" void kernel_launch(void* const* d_in, const int* in_sizes, int n_in,
                              void* d_out, int out_size, void* d_ws, size_t ws_size,
                              hipStream_t stream) {
    const float* emissions   = (const float*)d_in[0];
    const int*   lengths     = (const int*)d_in[1];
    const float* transitions = (const float*)d_in[2];
    const float* start_t     = (const float*)d_in[3];
    const float* end_t       = (const float*)d_in[4];
    float* out = (float*)d_out;

    crf_logz_kernel<<<BB * CC, NN, 0, stream>>>(
        emissions, lengths, transitions, start_t, end_t, out);
}

// Round 6
// 555.584 us; speedup vs baseline: 1.4641x; 1.1991x over previous
//
#include <hip/hip_runtime.h>

#define BB 64
#define TT 1024
#define CC 2
#define NN 128

#define REP16(M) M(0)M(1)M(2)M(3)M(4)M(5)M(6)M(7)M(8)M(9)M(10)M(11)M(12)M(13)M(14)M(15)

// fp32 -> bf16 bits, round-to-nearest-even (inputs are never NaN here)
static __device__ __forceinline__ unsigned f2bf(float x) {
    const unsigned u = __float_as_uint(x);
    return (u + 0x7FFFu + ((u >> 16) & 1u)) >> 16;
}
static __device__ __forceinline__ unsigned pk2(float lo, float hi) {
    return f2bf(lo) | (f2bf(hi) << 16);
}

// D.f32 += S0.bf16[0]*S1.bf16[0] + S0.bf16[1]*S1.bf16[1]  (VOP3P, VGPR-only
// sources — R4 proved v_dot2 rejects AGPR operands on gfx950).
#define DOT(acc, pp, ee) \
    asm("v_dot2_f32_bf16 %0, %1, %2, %0" : "+v"(acc) : "v"(pp), "v"(ee));

// ROUND-6: all 64 E words as PLAIN C constants, no asm pins, and the
// register budget raised explicitly. Series evidence: the allocator has
// been targeting ~64 arch VGPRs all along (R0 pinned-E: VGPR=44 with E
// AGPR-spilled + per-step restores; R5 32-plain-C: VGPR=64 exactly = 32 E
// + 32 others, LO half resident). waves_per_eu(1,1) alone did not raise
// the budget; amdgpu_num_vgpr(256) does it directly. Live pressure
// ~110 << 256, so E should finally be resident with ZERO per-step
// restore/reload instructions. Plain C values (R5-proven) let the
// scheduler do whatever it wants — no volatile, no dummy deps.
#define E_INIT(c) \
    const unsigned ue##c##_0 = pk2(__expf(tr[(8*(c)+0)*NN + j]), __expf(tr[(8*(c)+1)*NN + j])); \
    const unsigned ue##c##_1 = pk2(__expf(tr[(8*(c)+2)*NN + j]), __expf(tr[(8*(c)+3)*NN + j])); \
    const unsigned ue##c##_2 = pk2(__expf(tr[(8*(c)+4)*NN + j]), __expf(tr[(8*(c)+5)*NN + j])); \
    const unsigned ue##c##_3 = pk2(__expf(tr[(8*(c)+6)*NN + j]), __expf(tr[(8*(c)+7)*NN + j]));

// 8 MACs: one b128 broadcast read (4 packed p-pairs) + 4 dot2.
#define MV(c) { const uint4 q = pb[c]; \
    DOT(a0, q.x, ue##c##_0) DOT(a1, q.y, ue##c##_1) \
    DOT(a2, q.z, ue##c##_2) DOT(a3, q.w, ue##c##_3) }

// Raw workgroup barrier: producer-visibility via lgkmcnt(0) ONLY (global
// prefetch loads stay in flight across the barrier). WAR safety on the
// double-buffered p: each wave's lgkmcnt(0) at the NEXT barrier drains its
// reads before any wave re-writes that buffer two iterations later.
static __device__ __forceinline__ void wg_barrier() {
    asm volatile("s_waitcnt lgkmcnt(0)" ::: "memory");
    __builtin_amdgcn_s_barrier();
    asm volatile("" ::: "memory");
}

// One workgroup (128 thr = 2 waves) per (b,c) chain; thread j owns tag j
// and E column j as 64 packed-bf16 words in arch VGPRs.
//
// Critical-path factoring (kept): alpha_t = S_t + log(s_t) + e_t,
//   p_{t+1} = exp(alpha_t - S_{t+1}) = s_t * exp(S_t + e_t - S_{t+1})
// so __expf/__logf run off the serial chain (log only on thread 0's
// shift side-path, which has a full step of slack).
__global__ __launch_bounds__(128, 1)
__attribute__((amdgpu_waves_per_eu(1, 1), amdgpu_num_vgpr(256)))
void crf_logz_kernel(const float* __restrict__ emissions,
                     const int* __restrict__ lengths,
                     const float* __restrict__ transitions,
                     const float* __restrict__ start_trans,
                     const float* __restrict__ end_trans,
                     float* __restrict__ out)
{
    const int bc = blockIdx.x;
    const int b  = bc >> 1;
    const int c  = bc & 1;
    const int j  = threadIdx.x;            // 0..127, owns tag j

    __shared__ __align__(16) unsigned short pbufs[2][NN];  // bf16 p, double-buffered
    __shared__ float shbuf[2];             // shift broadcast (alpha_t[0]), parity-buffered
    __shared__ float red[NN];              // final reduction scratch

    const float* tr = transitions + c * NN * NN;
    REP16(E_INIT)                          // 64 plain VGPR words = 128 bf16 E values

    const int len  = lengths[b];           // in [T/2, T]
    const int tmax = len - 1;

    // emissions[b][t][c][*]; t-stride = CC*NN floats; coalesced per wave
    const float* emisb = emissions + ((size_t)b * TT * CC + c) * NN;

    const float alpha0 = start_trans[c * NN + j] + emisb[j];  // alpha_0[j]
    if (j == 0) shbuf[0] = alpha0;         // S_2 = alpha_0[0]; visible after barrier t=1

    // p_1 = exp(alpha_0 - S_1) with S_1 = 0 (|alpha_0| < ~12)
    unsigned pbits = f2bf(__expf(alpha0));
    float Scur = 0.f;                      // S_t for t = 1

    // 3-deep register emission pipeline (stays in flight across raw barriers;
    // ~3 steps of lead >> HBM latency even at low clock)
    const int t1 = (1 < tmax) ? 1 : tmax;
    const int t2 = (2 < tmax) ? 2 : tmax;
    const int t3 = (3 < tmax) ? 3 : tmax;
    float ec = emisb[(size_t)t1 * (CC * NN) + j];   // e_t
    float e1 = emisb[(size_t)t2 * (CC * NN) + j];   // e_{t+1}
    float e2 = emisb[(size_t)t3 * (CC * NN) + j];   // e_{t+2}

    float s = 0.f, Sfin = 0.f, efin = ec;

    for (int t = 1; t < len; ++t) {
        pbufs[t & 1][j] = (unsigned short)pbits;   // p_t, packed last iteration
        wg_barrier();                              // lgkm-only: vmcnt stays in flight

        // prefetch emission for t+3 (clamped); never drained by the barrier
        const int tp = (t + 3 <= tmax) ? (t + 3) : tmax;
        const float el = emisb[(size_t)tp * (CC * NN) + j];

        const float Snxt = shbuf[(t - 1) & 1];     // S_{t+1} = alpha_{t-1}[0]
        const float f = __expf(Scur + ec - Snxt);  // || with dots (no dep on s)

        const uint4* __restrict__ pb = (const uint4*)pbufs[t & 1];
        float a0 = 0.f, a1 = 0.f, a2 = 0.f, a3 = 0.f;
        REP16(MV)                          // 16 p-broadcasts + 64 dot2 (E resident)
        s = (a0 + a1) + (a2 + a3);         // s_t[j]

        // S_{t+2} = alpha_t[0]; thread 0's log has a step of slack
        if (j == 0) shbuf[t & 1] = Scur + __logf(s) + ec;

        pbits = f2bf(s * f);               // p_{t+1}[j] -> bf16 (critical: 1 mul + pack)

        Sfin = Scur; efin = ec;            // snapshot for epilogue
        Scur = Snxt; ec = e1; e1 = e2; e2 = el;
    }

    // alpha_{len-1}[j] = S_{len-1} + log(s_{len-1}[j]) + e_{len-1}[j]
    const float alpha = (tmax == 0) ? alpha0 : (Sfin + __logf(s) + efin);

    // final logsumexp over tags
    red[j] = alpha + end_trans[c * NN + j];
    __syncthreads();
    if (j < 64) {
        const float x = red[j], y = red[j + 64];
        float m = fmaxf(x, y);
        #pragma unroll
        for (int off = 32; off > 0; off >>= 1)
            m = fmaxf(m, __shfl_xor(m, off));
        float ssum = __expf(x - m) + __expf(y - m);
        #pragma unroll
        for (int off = 32; off > 0; off >>= 1)
            ssum += __shfl_xor(ssum, off);
        if (j == 0) out[b * CC + c] = m + __logf(ssum);
    }
}

extern "C" void kernel_launch(void* const* d_in, const int* in_sizes, int n_in,
                              void* d_out, int out_size, void* d_ws, size_t ws_size,
                              hipStream_t stream) {
    const float* emissions   = (const float*)d_in[0];
    const int*   lengths     = (const int*)d_in[1];
    const float* transitions = (const float*)d_in[2];
    const float* start_t     = (const float*)d_in[3];
    const float* end_t       = (const float*)d_in[4];
    float* out = (float*)d_out;

    crf_logz_kernel<<<BB * CC, NN, 0, stream>>>(
        emissions, lengths, transitions, start_t, end_t, out);
}